// Round 4
// baseline (691.598 us; speedup 1.0000x reference)
//
#include <hip/hip_runtime.h>
#include <stdint.h>

#define Tt 16
#define Cc 768
#define Ss 2048          // H*W*D
#define N1 2304
#define NH 12
#define HD 64
#define EPSV 1e-6f

typedef unsigned short ushort_t;
typedef __attribute__((ext_vector_type(8))) short short8;   // 8 bf16
typedef __attribute__((ext_vector_type(4))) short short4v;  // 4 bf16
typedef __attribute__((ext_vector_type(4))) float f32x4;

static __device__ __forceinline__ float b2f(unsigned short u) {
  union { unsigned int i; float f; } c;
  c.i = ((unsigned int)u) << 16;
  return c.f;
}
static __device__ __forceinline__ unsigned short f2b(float f) {
  union { float f; unsigned int i; } c;
  c.f = f;
  return (unsigned short)((c.i + 0x7fffu + ((c.i >> 16) & 1u)) >> 16);
}

// dual-dtype loaders: flag==1 -> input buffer is float32, else bf16
static __device__ __forceinline__ void load8(const void* p, size_t eoff,
                                             int isf32, float* o) {
  if (isf32) {
    const float* f = (const float*)p + eoff;
    f32x4 a = *(const f32x4*)f;
    f32x4 b = *(const f32x4*)(f + 4);
    o[0] = a[0]; o[1] = a[1]; o[2] = a[2]; o[3] = a[3];
    o[4] = b[0]; o[5] = b[1]; o[6] = b[2]; o[7] = b[3];
  } else {
    short8 d = *(const short8*)((const ushort_t*)p + eoff);
#pragma unroll
    for (int e = 0; e < 8; e++) o[e] = b2f((unsigned short)d[e]);
  }
}
static __device__ __forceinline__ float load1(const void* p, size_t eoff, int isf32) {
  return isf32 ? ((const float*)p)[eoff] : b2f(((const ushort_t*)p)[eoff]);
}

#define GLP(p) ((const __attribute__((address_space(1))) void*)(p))
#define LDSP(p) ((__attribute__((address_space(3))) void*)(p))

// ---------------------------------------------------------------- kernel 0
__global__ __launch_bounds__(256) void detect_k(const ushort_t* __restrict__ x,
                                               int* __restrict__ flag) {
  __shared__ int sbad;
  if (threadIdx.x == 0) sbad = 0;
  __syncthreads();
  int bad = 0;
  for (int i = threadIdx.x; i < 65536; i += 256) {
    const unsigned int e = (x[i] >> 7) & 0xFFu;
    if (e == 0xFFu) bad = 1;
  }
  if (bad) atomicOr(&sbad, 1);
  __syncthreads();
  if (threadIdx.x == 0) flag[0] = sbad;
}

// ---------------------------------------------------------------- kernel 0b
__global__ __launch_bounds__(256) void cvt_big_k(const void* __restrict__ src,
                                                ushort_t* __restrict__ dst,
                                                int n8, const int* __restrict__ flag) {
  const int isf32 = *flag;
  const int i = blockIdx.x * 256 + threadIdx.x;
  if (i >= n8) return;
  float o[8];
  load8(src, (size_t)i * 8, isf32, o);
  short8 v;
#pragma unroll
  for (int e = 0; e < 8; e++) v[e] = (short)f2b(o[e]);
  *(short8*)(dst + (size_t)i * 8) = v;
}

__global__ __launch_bounds__(256) void cvt_small_k(
    const void* w1, const void* bin, const void* bo, const void* qs,
    const void* qb, const void* ks, const void* kb, const void* relb,
    ushort_t* __restrict__ dst, const int* __restrict__ flag) {
  const int isf32 = *flag;
  const void* srcs[8] = {w1, bin, bo, qs, qb, ks, kb, relb};
  const int sizes[8] = {768, 2304, 768, 64, 64, 64, 64, 384};
  int off = 0;
#pragma unroll
  for (int s = 0; s < 8; s++) {
    for (int i = threadIdx.x; i < sizes[s]; i += 256)
      dst[off + i] = isf32 ? f2b(((const float*)srcs[s])[i])
                           : ((const ushort_t*)srcs[s])[i];
    off += sizes[s];
  }
}

// ---------------------------------------------------------------- kernel 1
__global__ __launch_bounds__(256) void rms_stats_k(
    const void* __restrict__ x, const int* __restrict__ flag,
    float* __restrict__ invrms) {
  const int isf32 = *flag;
  const int t = blockIdx.x / NH;
  const int g = blockIdx.x % NH;
  const size_t base = ((size_t)(t * Cc + g * 64)) * Ss;
  float ss = 0.f;
  for (int v = threadIdx.x; v < 16384; v += 256) {
    const int ci = v >> 8;
    const int sj = (v & 255) << 3;
    float o[8];
    load8(x, base + (size_t)ci * Ss + sj, isf32, o);
#pragma unroll
    for (int e = 0; e < 8; e++) ss += o[e] * o[e];
  }
#pragma unroll
  for (int m = 1; m < 64; m <<= 1) ss += __shfl_xor(ss, m);
  __shared__ float red[4];
  if ((threadIdx.x & 63) == 0) red[threadIdx.x >> 6] = ss;
  __syncthreads();
  if (threadIdx.x == 0) {
    float tot = red[0] + red[1] + red[2] + red[3];
    invrms[blockIdx.x] = rsqrtf(tot * (1.f / 131072.f) + EPSV);
  }
}

// ---------------------------------------------------------------- kernel 2
__global__ __launch_bounds__(256) void norm_chunk_k(
    const void* __restrict__ x, const int* __restrict__ flag,
    const ushort_t* __restrict__ w1, const float* __restrict__ invrms,
    ushort_t* __restrict__ xnc, int s0c, int chl) {
  __shared__ __align__(16) ushort_t tile[64][64];
  const int isf32 = *flag;
  const int t = blockIdx.z;
  const int c0 = blockIdx.y * 64;
  const int sl0 = blockIdx.x * 64;
  const float ir = invrms[t * NH + (c0 >> 6)];
  const int tid = threadIdx.x;
  for (int v = tid; v < 512; v += 256) {
    const int ci = v >> 3;
    const int q = v & 7;
    float o[8];
    load8(x, ((size_t)(t * Cc + c0 + ci)) * Ss + s0c + sl0 + q * 8, isf32, o);
    const float sc = ir * b2f(w1[c0 + ci]);
    short8 w;
#pragma unroll
    for (int e = 0; e < 8; e++) w[e] = (short)f2b(o[e] * sc);
    *(short8*)&tile[ci][(q ^ (ci >> 3)) * 8] = w;
  }
  __syncthreads();
  for (int v = tid; v < 512; v += 256) {
    const int sj = v >> 3;
    const int cb = (v & 7) * 8;
    const int sw = (sj >> 3) ^ (v & 7);
    const int so = sj & 7;
    short8 o;
#pragma unroll
    for (int e = 0; e < 8; e++) o[e] = (short)tile[cb + e][sw * 8 + so];
    *(short8*)(xnc + ((size_t)(t * chl + sl0 + sj)) * Cc + c0 + cb) = o;
  }
}

// ---------------------------------------------------------------- kernel 3a
// (fallback for small-ws chunked path) 128x128 m97-pattern GEMM
__global__ __launch_bounds__(256, 2) void gemm_qkv_k(
    const ushort_t* __restrict__ A, const ushort_t* __restrict__ Bw,
    const ushort_t* __restrict__ bias, ushort_t* __restrict__ Cout) {
  __shared__ __align__(16) ushort_t As[128 * 32];
  __shared__ __align__(16) ushort_t Bs[128 * 32];
  const int tid = threadIdx.x;
  const int bm0 = blockIdx.x * 128;
  const int bn0 = blockIdx.y * 128;
  const int lane = tid & 63;
  const int wave = tid >> 6;
  const int wm = (wave >> 1) << 6;
  const int wn = (wave & 1) << 6;
  f32x4 acc[4][4];
#pragma unroll
  for (int i = 0; i < 4; i++)
#pragma unroll
    for (int j = 0; j < 4; j++) acc[i][j] = (f32x4){0.f, 0.f, 0.f, 0.f};
  const int srow = tid >> 2;
  const int scol = (tid & 3) << 3;
  const ushort_t* ag = A + (size_t)(bm0 + srow) * Cc + scol;
  const ushort_t* bg = Bw + (size_t)(bn0 + srow) * Cc + scol;
  ushort_t* la = As + tid * 8;
  ushort_t* lb = Bs + tid * 8;
  const int frow = lane & 15;
  const int koff = (lane >> 4) << 3;
  for (int kt = 0; kt < Cc; kt += 32) {
    __syncthreads();
    __builtin_amdgcn_global_load_lds(GLP(ag + kt), LDSP(la), 16, 0, 0);
    __builtin_amdgcn_global_load_lds(GLP(ag + kt + 64 * Cc), LDSP(la + 2048), 16, 0, 0);
    __builtin_amdgcn_global_load_lds(GLP(bg + kt), LDSP(lb), 16, 0, 0);
    __builtin_amdgcn_global_load_lds(GLP(bg + kt + 64 * Cc), LDSP(lb + 2048), 16, 0, 0);
    __syncthreads();
    short8 af[4], bf[4];
#pragma unroll
    for (int i = 0; i < 4; i++)
      af[i] = *(const short8*)(As + (wm + i * 16 + frow) * 32 + koff);
#pragma unroll
    for (int j = 0; j < 4; j++)
      bf[j] = *(const short8*)(Bs + (wn + j * 16 + frow) * 32 + koff);
#pragma unroll
    for (int i = 0; i < 4; i++)
#pragma unroll
      for (int j = 0; j < 4; j++)
        acc[i][j] = __builtin_amdgcn_mfma_f32_16x16x32_bf16(af[i], bf[j], acc[i][j], 0, 0, 0);
  }
  const int mq = (lane >> 4) << 2;
  const int nl = lane & 15;
#pragma unroll
  for (int j = 0; j < 4; j++) {
    const int col = bn0 + wn + j * 16 + nl;
    const float bc = b2f(bias[col]);
#pragma unroll
    for (int i = 0; i < 4; i++) {
#pragma unroll
      for (int r = 0; r < 4; r++) {
        const int row = bm0 + wm + i * 16 + mq + r;
        Cout[(size_t)row * N1 + col] = f2b(acc[i][j][r] + bc);
      }
    }
  }
}

// ---------------------------------------------------------------- kernel 3b
// 256x256 BK=64 8-wave GEMM, true 8-phase counted-vmcnt pipeline (T1-T5).
// K-HALF decomposition: LDS [dbuf][A|B][khalf][256 rows x 32 elems].
// Staging stream per K-tile (FIFO): [A-kh0, B-kh0, A-kh1, B-kh1], one unit
// (2 global_load_lds ops) issued per phase. Phases 0-1 consume kh0 only,
// phases 2-3 consume kh1 only -- uniform across ALL waves, so phase
// consumption order == staging FIFO order and counted waits are race-free
// (R2 lesson). Ledger per wave (ops): enter tile with 4 outstanding
// (this tile's kh1 pair); ph0 +2 =6; ph1 +2 =8, wait vmcnt(4) -> this
// tile's kh1 landed, next tile's kh0 pair (4) in flight; ph2 +2 =6;
// ph3 +2 =8, wait vmcnt(4) -> next kh0 landed, its kh1 in flight. Never 0.
// Swizzle: 4x16B slots per 64B row; phys_slot = log_slot ^ ((row>>1)&3).
// Stage writes linear (dest = base + tid*16B) with inverse-swizzled global
// source column (involution, rule #21); frag reads apply the same XOR.
// Bank balance: 16 lanes/k-group spread over 8 slot-positions x2 = 2-way (free).
static __device__ __forceinline__ void rdA4(short8 af[4], const ushort_t* base,
                                            int ar, int mib, int ck) {
#pragma unroll
  for (int mi = 0; mi < 4; mi++)
    af[mi] = *(const short8*)&base[(ar + (mib + mi) * 16) * 32 + ck];
}
static __device__ __forceinline__ void rdB4(short8 bf[4], const ushort_t* base,
                                            int br, int ck) {
#pragma unroll
  for (int ni = 0; ni < 4; ni++)
    bf[ni] = *(const short8*)&base[(br + ni * 16) * 32 + ck];
}
template <int MIB>
static __device__ __forceinline__ void mmq(f32x4 (&acc)[8][4], const short8 af[4],
                                           const short8 bf[4]) {
#pragma unroll
  for (int mi = 0; mi < 4; mi++)
#pragma unroll
    for (int ni = 0; ni < 4; ni++)
      acc[MIB + mi][ni] = __builtin_amdgcn_mfma_f32_16x16x32_bf16(
          af[mi], bf[ni], acc[MIB + mi][ni], 0, 0, 0);
}
#define QPH_BAR { __builtin_amdgcn_sched_barrier(0); __builtin_amdgcn_s_barrier(); \
                  __builtin_amdgcn_sched_barrier(0); }

__global__ __launch_bounds__(512, 2) void gemm_qkv256_k(
    const ushort_t* __restrict__ A, const ushort_t* __restrict__ Bw,
    const ushort_t* __restrict__ bias, ushort_t* __restrict__ Cout) {
  __shared__ __align__(16) ushort_t lds[2][2][2][8192];  // [buf][A/B][khalf][256x32]
  const int tid = threadIdx.x;
  const int lane = tid & 63;
  const int wave = tid >> 6;
  const int wr = wave >> 2;  // 0..1
  const int wc = wave & 3;   // 0..3
  // T1: XCD-bijective remap (1152 = 8*144), bn fast within chunk
  const int wg = ((int)blockIdx.x & 7) * 144 + ((int)blockIdx.x >> 3);
  const int bm0 = (wg / 9) * 256;
  const int bn0 = (wg % 9) * 256;
  // staging: thread t -> row = sub*128 + (t>>2), phys slot = t&3 (linear LDS),
  // logical slot = (t&3) ^ ((t>>3)&3) (inverse swizzle on global column)
  const int srow = tid >> 2;                              // 0..127
  const int scol = ((tid & 3) ^ ((tid >> 3) & 3)) << 3;   // elem 0..24
  const ushort_t* ag = A + (size_t)(bm0 + srow) * Cc + scol;
  const ushort_t* bg = Bw + (size_t)(bn0 + srow) * Cc + scol;
#define STGA(p, kh, kt) { \
    __builtin_amdgcn_global_load_lds(GLP(ag + (kt) + (kh) * 32), \
        LDSP(&lds[p][0][kh][tid * 8]), 16, 0, 0); \
    __builtin_amdgcn_global_load_lds(GLP(ag + 128 * Cc + (kt) + (kh) * 32), \
        LDSP(&lds[p][0][kh][4096 + tid * 8]), 16, 0, 0); \
  }
#define STGB(p, kh, kt) { \
    __builtin_amdgcn_global_load_lds(GLP(bg + (kt) + (kh) * 32), \
        LDSP(&lds[p][1][kh][tid * 8]), 16, 0, 0); \
    __builtin_amdgcn_global_load_lds(GLP(bg + 128 * Cc + (kt) + (kh) * 32), \
        LDSP(&lds[p][1][kh][4096 + tid * 8]), 16, 0, 0); \
  }
  // frag-read constants: row = base + (lane&15); phys slot = (lane>>4)^((lane>>1)&3)
  const int ck = (((lane >> 4) ^ ((lane >> 1) & 3)) << 3);
  const int ar = wr * 128 + (lane & 15);
  const int br = wc * 64 + (lane & 15);
  f32x4 acc[8][4];
#pragma unroll
  for (int i = 0; i < 8; i++)
#pragma unroll
    for (int j = 0; j < 4; j++) acc[i][j] = (f32x4){0.f, 0.f, 0.f, 0.f};
  short8 af[4], bf[4];
  // ---- prologue: stage tile 0 in stream order; kh0 landed, kh1 in flight
  STGA(0, 0, 0); STGB(0, 0, 0); STGA(0, 1, 0); STGB(0, 1, 0);
  asm volatile("s_waitcnt vmcnt(4)");
  QPH_BAR;
  // ---- main loop: tiles 0..10 (tile t+1 staged during tile t)
  for (int t = 0; t < 11; t++) {
    const int p = t & 1;
    const int q = p ^ 1;
    const int kt = (t + 1) * 64;
    // phase 0 (kh0): A mi0-3 + B ni0-3; stage A-kh0(t+1)
    rdA4(af, &lds[p][0][0][0], ar, 0, ck);
    rdB4(bf, &lds[p][1][0][0], br, ck);
    STGA(q, 0, kt);
    QPH_BAR;
    __builtin_amdgcn_s_setprio(1);
    mmq<0>(acc, af, bf);
    __builtin_amdgcn_s_setprio(0);
    QPH_BAR;
    // phase 1 (kh0): A mi4-7 (B reused); stage B-kh0(t+1); wait kh1(t)
    rdA4(af, &lds[p][0][0][0], ar, 4, ck);
    STGB(q, 0, kt);
    QPH_BAR;
    __builtin_amdgcn_s_setprio(1);
    mmq<4>(acc, af, bf);
    __builtin_amdgcn_s_setprio(0);
    __builtin_amdgcn_sched_barrier(0);
    asm volatile("s_waitcnt vmcnt(4)");   // tile t kh1 pair landed
    QPH_BAR;
    // phase 2 (kh1): A mi0-3 + B ni0-3; stage A-kh1(t+1)
    rdA4(af, &lds[p][0][1][0], ar, 0, ck);
    rdB4(bf, &lds[p][1][1][0], br, ck);
    STGA(q, 1, kt);
    QPH_BAR;
    __builtin_amdgcn_s_setprio(1);
    mmq<0>(acc, af, bf);
    __builtin_amdgcn_s_setprio(0);
    QPH_BAR;
    // phase 3 (kh1): A mi4-7; stage B-kh1(t+1); wait kh0(t+1)
    rdA4(af, &lds[p][0][1][0], ar, 4, ck);
    STGB(q, 1, kt);
    QPH_BAR;
    __builtin_amdgcn_s_setprio(1);
    mmq<4>(acc, af, bf);
    __builtin_amdgcn_s_setprio(0);
    __builtin_amdgcn_sched_barrier(0);
    asm volatile("s_waitcnt vmcnt(4)");   // tile t+1 kh0 pair landed
    QPH_BAR;
  }
  {  // ---- last tile t=11 (p=1): no staging; drain kh1 before phase 2
    rdA4(af, &lds[1][0][0][0], ar, 0, ck);
    rdB4(bf, &lds[1][1][0][0], br, ck);
    QPH_BAR;
    __builtin_amdgcn_s_setprio(1);
    mmq<0>(acc, af, bf);
    __builtin_amdgcn_s_setprio(0);
    QPH_BAR;
    rdA4(af, &lds[1][0][0][0], ar, 4, ck);
    QPH_BAR;
    __builtin_amdgcn_s_setprio(1);
    mmq<4>(acc, af, bf);
    __builtin_amdgcn_s_setprio(0);
    __builtin_amdgcn_sched_barrier(0);
    asm volatile("s_waitcnt vmcnt(0)");   // kh1 pair (last outstanding) landed
    QPH_BAR;
    rdA4(af, &lds[1][0][1][0], ar, 0, ck);
    rdB4(bf, &lds[1][1][1][0], br, ck);
    QPH_BAR;
    __builtin_amdgcn_s_setprio(1);
    mmq<0>(acc, af, bf);
    __builtin_amdgcn_s_setprio(0);
    QPH_BAR;
    rdA4(af, &lds[1][0][1][0], ar, 4, ck);
    __builtin_amdgcn_s_setprio(1);
    mmq<4>(acc, af, bf);
    __builtin_amdgcn_s_setprio(0);
  }
  // ---- epilogue
  const int mq = (lane >> 4) << 2;
  const int nl = lane & 15;
#pragma unroll
  for (int ni = 0; ni < 4; ni++) {
    const int col = bn0 + wc * 64 + ni * 16 + nl;
    const float bc = b2f(bias[col]);
#pragma unroll
    for (int mi = 0; mi < 8; mi++) {
#pragma unroll
      for (int r = 0; r < 4; r++) {
        const int row = bm0 + wr * 128 + mi * 16 + mq + r;
        Cout[(size_t)row * N1 + col] = f2b(acc[mi][ni][r] + bc);
      }
    }
  }
#undef STGA
#undef STGB
}

// ---------------------------------------------------------------- kernel 4
// wave-per-(sl,h): chl*12 independent 16x16x64 attention problems.
__global__ __launch_bounds__(256) void attention_k(
    const ushort_t* __restrict__ qkvc, const ushort_t* __restrict__ qs,
    const ushort_t* __restrict__ qb, const ushort_t* __restrict__ ks,
    const ushort_t* __restrict__ kb, const ushort_t* __restrict__ relb,
    ushort_t* __restrict__ aoc, int chl) {
  __shared__ __align__(16) float qf[4][16][68];
  __shared__ __align__(16) float kf[4][16][68];
  __shared__ __align__(16) float vf[4][16][68];
  __shared__ __align__(16) float attw[4][16][20];
  __shared__ __align__(16) float lnw[4][64];   // qs,qb,ks,kb fp32
  const int tid = threadIdx.x;
  const int wave = tid >> 6;
  const int lane = tid & 63;
  if (tid < 64) {
    lnw[0][tid] = b2f(qs[tid]);
    lnw[1][tid] = b2f(qb[tid]);
    lnw[2][tid] = b2f(ks[tid]);
    lnw[3][tid] = b2f(kb[tid]);
  }
  const int p = blockIdx.x * 4 + wave;
  const int sl = p / 12;
  const int h = p - sl * 12;
  const ushort_t* src = qkvc + (size_t)sl * N1 + h * 192;
  const size_t tstride = (size_t)chl * N1;
#pragma unroll
  for (int t = 0; t < 16; t++) {
    const ushort_t* r = src + (size_t)t * tstride;
    qf[wave][t][lane] = b2f(r[lane]);
    kf[wave][t][lane] = b2f(r[64 + lane]);
    vf[wave][t][lane] = b2f(r[128 + lane]);
  }
  __syncthreads();
  {
    const int row = lane >> 1;
    const int half = lane & 1;
    float* buf = (row < 16) ? &qf[wave][row][0] : &kf[wave][row - 16][0];
    const float* sc = (row < 16) ? lnw[0] : lnw[2];
    const float* bi = (row < 16) ? lnw[1] : lnw[3];
    f32x4* bp = (f32x4*)(buf + half * 32);
    f32x4 v4[8];
    float s = 0.f;
#pragma unroll
    for (int q4 = 0; q4 < 8; q4++) {
      v4[q4] = bp[q4];
      s += v4[q4][0] + v4[q4][1] + v4[q4][2] + v4[q4][3];
    }
    s += __shfl_xor(s, 1);
    const float mu = s * (1.f / 64.f);
    float va = 0.f;
#pragma unroll
    for (int q4 = 0; q4 < 8; q4++) {
#pragma unroll
      for (int e = 0; e < 4; e++) {
        const float d = v4[q4][e] - mu;
        va += d * d;
      }
    }
    va += __shfl_xor(va, 1);
    const float rs = rsqrtf(va * (1.f / 64.f) + EPSV);
    const f32x4* sc4 = (const f32x4*)(sc + half * 32);
    const f32x4* bi4 = (const f32x4*)(bi + half * 32);
#pragma unroll
    for (int q4 = 0; q4 < 8; q4++) {
      f32x4 scv = sc4[q4], biv = bi4[q4], o;
#pragma unroll
      for (int e = 0; e < 4; e++) o[e] = (v4[q4][e] - mu) * rs * scv[e] + biv[e];
      bp[q4] = o;
    }
  }
  __syncthreads();
  const int g = lane >> 4;
  const int t2 = lane & 15;
#pragma unroll
  for (int it = 0; it < 4; it++) {
    const int t1 = it * 4 + g;
    const f32x4* qrow = (const f32x4*)&qf[wave][t1][0];
    const f32x4* krow = (const f32x4*)&kf[wave][t2][0];
    float sco = 0.f;
#pragma unroll
    for (int q4 = 0; q4 < 16; q4++) {
      f32x4 a = qrow[q4], b = krow[q4];
      sco += a[0] * b[0] + a[1] * b[1] + a[2] * b[2] + a[3] * b[3];
    }
    const int rp = t2 - t1;
    int bkt = (rp > 0) ? 16 : 0;
    const int n = (rp < 0) ? -rp : rp;
    if (n < 8) {
      bkt += n;
    } else {
      int vl = 8 + (int)(__logf((float)n * 0.125f) * 2.8853900817779268f);
      bkt += (vl < 15) ? vl : 15;
    }
    sco = sco * 0.125f + b2f(relb[bkt * NH + h]);
    float mx = sco;
#pragma unroll
    for (int m = 8; m >= 1; m >>= 1) mx = fmaxf(mx, __shfl_xor(mx, m));
    const float ex = __expf(sco - mx);
    float sm = ex;
#pragma unroll
    for (int m = 8; m >= 1; m >>= 1) sm += __shfl_xor(sm, m);
    attw[wave][t1][t2] = ex / sm;
  }
  __syncthreads();
  const int jq = lane & 15;
#pragma unroll
  for (int it = 0; it < 4; it++) {
    const int t1 = it * 4 + g;
    const f32x4* arow2 = (const f32x4*)&attw[wave][t1][0];
    f32x4 o = (f32x4){0.f, 0.f, 0.f, 0.f};
#pragma unroll
    for (int tq = 0; tq < 4; tq++) {
      f32x4 aw = arow2[tq];
#pragma unroll
      for (int e = 0; e < 4; e++) {
        f32x4 vv = *(const f32x4*)&vf[wave][tq * 4 + e][jq * 4];
        o[0] += aw[e] * vv[0];
        o[1] += aw[e] * vv[1];
        o[2] += aw[e] * vv[2];
        o[3] += aw[e] * vv[3];
      }
    }
    short4v st;
#pragma unroll
    for (int e = 0; e < 4; e++) st[e] = (short)f2b(o[e]);
    *(short4v*)(aoc + ((size_t)(t1 * chl + sl)) * Cc + h * HD + jq * 4) = st;
  }
}

// ---------------------------------------------------------------- kernel 5
// D[c_out][r] = wo[c_out][:] . aoc[r][:]; fused +bias +residual -> y (f32)
__global__ __launch_bounds__(256, 2) void gemm_out_k(
    const ushort_t* __restrict__ A, const ushort_t* __restrict__ Bm,
    const ushort_t* __restrict__ bias, const void* __restrict__ xres,
    const int* __restrict__ flag, float* __restrict__ y, int s0c,
    int chl, int lgchl) {
  __shared__ __align__(16) ushort_t As[128 * 32];
  __shared__ __align__(16) ushort_t Bs[128 * 32];
  const int isf32 = *flag;
  const int tid = threadIdx.x;
  // XCD-bijective remap when grid divisible by 8; bm fast (shares aoc panel)
  int bmt = blockIdx.x, bnt = blockIdx.y;
  {
    const int nwg = gridDim.x * gridDim.y;
    if ((nwg & 7) == 0) {
      const int hw = (int)blockIdx.x + (int)blockIdx.y * gridDim.x;
      const int cpx = nwg >> 3;
      const int w = (hw & 7) * cpx + (hw >> 3);
      bmt = w % gridDim.x;
      bnt = w / gridDim.x;
    }
  }
  const int bm0 = bmt * 128;  // c_out
  const int bn0 = bnt * 128;  // r (chunk row)
  const int lane = tid & 63;
  const int wave = tid >> 6;
  const int wm = (wave >> 1) << 6;
  const int wn = (wave & 1) << 6;
  f32x4 acc[4][4];
#pragma unroll
  for (int i = 0; i < 4; i++)
#pragma unroll
    for (int j = 0; j < 4; j++) acc[i][j] = (f32x4){0.f, 0.f, 0.f, 0.f};
  const int srow = tid >> 2;
  const int scol = (tid & 3) << 3;
  const ushort_t* ag = A + (size_t)(bm0 + srow) * Cc + scol;
  const ushort_t* bg = Bm + (size_t)(bn0 + srow) * Cc + scol;
  ushort_t* la = As + tid * 8;
  ushort_t* lb = Bs + tid * 8;
  const int frow = lane & 15;
  const int koff = (lane >> 4) << 3;
  for (int kt = 0; kt < Cc; kt += 32) {
    __syncthreads();
    __builtin_amdgcn_global_load_lds(GLP(ag + kt), LDSP(la), 16, 0, 0);
    __builtin_amdgcn_global_load_lds(GLP(ag + kt + 64 * Cc), LDSP(la + 2048), 16, 0, 0);
    __builtin_amdgcn_global_load_lds(GLP(bg + kt), LDSP(lb), 16, 0, 0);
    __builtin_amdgcn_global_load_lds(GLP(bg + kt + 64 * Cc), LDSP(lb + 2048), 16, 0, 0);
    __syncthreads();
    short8 af[4], bf[4];
#pragma unroll
    for (int i = 0; i < 4; i++)
      af[i] = *(const short8*)(As + (wm + i * 16 + frow) * 32 + koff);
#pragma unroll
    for (int j = 0; j < 4; j++)
      bf[j] = *(const short8*)(Bs + (wn + j * 16 + frow) * 32 + koff);
#pragma unroll
    for (int i = 0; i < 4; i++)
#pragma unroll
      for (int j = 0; j < 4; j++)
        acc[i][j] = __builtin_amdgcn_mfma_f32_16x16x32_bf16(af[i], bf[j], acc[i][j], 0, 0, 0);
  }
  const int mq = (lane >> 4) << 2;
  const int nl = lane & 15;
#pragma unroll
  for (int j = 0; j < 4; j++) {
    const int col = bn0 + wn + j * 16 + nl;  // chunk row r
    const int t = col >> lgchl;              // r / chl
    const int sp = s0c + (col & (chl - 1));  // global spatial
#pragma unroll
    for (int i = 0; i < 4; i++) {
#pragma unroll
      for (int r = 0; r < 4; r++) {
        const int cch = bm0 + wm + i * 16 + mq + r;  // c_out
        const size_t off = ((size_t)(t * Cc + cch)) * Ss + sp;
        y[off] = acc[i][j][r] + b2f(bias[cch]) + load1(xres, off, isf32);
      }
    }
  }
}

// ----------------------------------------------------------------
extern "C" void kernel_launch(void* const* d_in, const int* in_sizes, int n_in,
                              void* d_out, int out_size, void* d_ws, size_t ws_size,
                              hipStream_t stream) {
  (void)in_sizes; (void)n_in; (void)out_size;
  const void* x   = d_in[0];
  const void* w1  = d_in[1];
  const void* win = d_in[2];
  const void* bin = d_in[3];
  const void* qsc = d_in[4];
  const void* qbi = d_in[5];
  const void* ksc = d_in[6];
  const void* kbi = d_in[7];
  const void* rbt = d_in[8];
  const void* wo  = d_in[9];
  const void* bo  = d_in[10];
  float* y = (float*)d_out;   // reference output dtype = float32

  char* ws = (char*)d_ws;
  int* flag      = (int*)ws;
  ushort_t* smallw = (ushort_t*)(ws + 4096);
  ushort_t* w1b  = smallw;
  ushort_t* binb = smallw + 768;
  ushort_t* bob  = smallw + 3072;
  ushort_t* qsb  = smallw + 3840;
  ushort_t* qbb  = smallw + 3904;
  ushort_t* ksb  = smallw + 3968;
  ushort_t* kbb  = smallw + 4032;
  ushort_t* relbb = smallw + 4096;
  float* invrms  = (float*)(ws + 1024);
  ushort_t* winb = (ushort_t*)(ws + 20480);
  ushort_t* wob  = (ushort_t*)(ws + 3559424);
  const size_t fixed = 4739072;  // end of wob

  // Adaptive chunk length (falls back to chunked schedule on small ws)
  const size_t per_row = (size_t)(Cc * 2 + N1 * 2 + Cc * 2);  // 7680 B
  int chl = Ss;
  while (chl > 64 && fixed + (size_t)Tt * chl * per_row > ws_size) chl >>= 1;
  int lgchl = 0;
  while ((1 << (lgchl + 1)) <= chl) lgchl++;

  ushort_t* xnc  = (ushort_t*)(ws + fixed);
  ushort_t* qkvc = xnc + (size_t)Tt * chl * Cc;
  ushort_t* aoc  = qkvc + (size_t)Tt * chl * N1;

  detect_k<<<1, 256, 0, stream>>>((const ushort_t*)x, flag);
  cvt_small_k<<<1, 256, 0, stream>>>(w1, bin, bo, qsc, qbi, ksc, kbi, rbt, smallw, flag);
  cvt_big_k<<<1769472 / 8 / 256, 256, 0, stream>>>(win, winb, 1769472 / 8, flag);
  cvt_big_k<<<589824 / 8 / 256, 256, 0, stream>>>(wo, wob, 589824 / 8, flag);
  rms_stats_k<<<dim3(Tt * NH), 256, 0, stream>>>(x, flag, invrms);
  for (int s0c = 0; s0c < Ss; s0c += chl) {
    norm_chunk_k<<<dim3(chl / 64, Cc / 64, Tt), 256, 0, stream>>>(x, flag, w1b, invrms, xnc, s0c, chl);
    if (chl == Ss) {
      // single-pass: M=32768 -> 128 x 9 = 1152 wgs (256^2 8-phase kernel)
      gemm_qkv256_k<<<dim3(1152), 512, 0, stream>>>(xnc, winb, binb, qkvc);
    } else {
      gemm_qkv_k<<<dim3(Tt * chl / 128, N1 / 128), 256, 0, stream>>>(xnc, winb, binb, qkvc);
    }
    attention_k<<<dim3(chl * NH / 4), 256, 0, stream>>>(qkvc, qsb, qbb, ksb, kbb, relbb, aoc, chl);
    gemm_out_k<<<dim3(Cc / 128, Tt * chl / 128), 256, 0, stream>>>(wob, aoc, bob, x, flag, y, s0c, chl, lgchl);
  }
}

// Round 5
// 658.051 us; speedup vs baseline: 1.0510x; 1.0510x over previous
//
#include <hip/hip_runtime.h>
#include <stdint.h>

#define Tt 16
#define Cc 768
#define Ss 2048          // H*W*D
#define N1 2304
#define NH 12
#define HD 64
#define EPSV 1e-6f

typedef unsigned short ushort_t;
typedef __attribute__((ext_vector_type(8))) short short8;   // 8 bf16
typedef __attribute__((ext_vector_type(4))) short short4v;  // 4 bf16
typedef __attribute__((ext_vector_type(4))) float f32x4;

static __device__ __forceinline__ float b2f(unsigned short u) {
  union { unsigned int i; float f; } c;
  c.i = ((unsigned int)u) << 16;
  return c.f;
}
static __device__ __forceinline__ unsigned short f2b(float f) {
  union { float f; unsigned int i; } c;
  c.f = f;
  return (unsigned short)((c.i + 0x7fffu + ((c.i >> 16) & 1u)) >> 16);
}

// dual-dtype loaders: flag==1 -> input buffer is float32, else bf16
static __device__ __forceinline__ void load8(const void* p, size_t eoff,
                                             int isf32, float* o) {
  if (isf32) {
    const float* f = (const float*)p + eoff;
    f32x4 a = *(const f32x4*)f;
    f32x4 b = *(const f32x4*)(f + 4);
    o[0] = a[0]; o[1] = a[1]; o[2] = a[2]; o[3] = a[3];
    o[4] = b[0]; o[5] = b[1]; o[6] = b[2]; o[7] = b[3];
  } else {
    short8 d = *(const short8*)((const ushort_t*)p + eoff);
#pragma unroll
    for (int e = 0; e < 8; e++) o[e] = b2f((unsigned short)d[e]);
  }
}
static __device__ __forceinline__ float load1(const void* p, size_t eoff, int isf32) {
  return isf32 ? ((const float*)p)[eoff] : b2f(((const ushort_t*)p)[eoff]);
}

#define GLP(p) ((const __attribute__((address_space(1))) void*)(p))
#define LDSP(p) ((__attribute__((address_space(3))) void*)(p))

// ---------------------------------------------------------------- kernel 0
__global__ __launch_bounds__(256) void detect_k(const ushort_t* __restrict__ x,
                                               int* __restrict__ flag) {
  __shared__ int sbad;
  if (threadIdx.x == 0) sbad = 0;
  __syncthreads();
  int bad = 0;
  for (int i = threadIdx.x; i < 65536; i += 256) {
    const unsigned int e = (x[i] >> 7) & 0xFFu;
    if (e == 0xFFu) bad = 1;
  }
  if (bad) atomicOr(&sbad, 1);
  __syncthreads();
  if (threadIdx.x == 0) flag[0] = sbad;
}

// ---------------------------------------------------------------- kernel 0b
__global__ __launch_bounds__(256) void cvt_big_k(const void* __restrict__ src,
                                                ushort_t* __restrict__ dst,
                                                int n8, const int* __restrict__ flag) {
  const int isf32 = *flag;
  const int i = blockIdx.x * 256 + threadIdx.x;
  if (i >= n8) return;
  float o[8];
  load8(src, (size_t)i * 8, isf32, o);
  short8 v;
#pragma unroll
  for (int e = 0; e < 8; e++) v[e] = (short)f2b(o[e]);
  *(short8*)(dst + (size_t)i * 8) = v;
}

__global__ __launch_bounds__(256) void cvt_small_k(
    const void* w1, const void* bin, const void* bo, const void* qs,
    const void* qb, const void* ks, const void* kb, const void* relb,
    ushort_t* __restrict__ dst, const int* __restrict__ flag) {
  const int isf32 = *flag;
  const void* srcs[8] = {w1, bin, bo, qs, qb, ks, kb, relb};
  const int sizes[8] = {768, 2304, 768, 64, 64, 64, 64, 384};
  int off = 0;
#pragma unroll
  for (int s = 0; s < 8; s++) {
    for (int i = threadIdx.x; i < sizes[s]; i += 256)
      dst[off + i] = isf32 ? f2b(((const float*)srcs[s])[i])
                           : ((const ushort_t*)srcs[s])[i];
    off += sizes[s];
  }
}

// ---------------------------------------------------------------- kernel 1
__global__ __launch_bounds__(256) void rms_stats_k(
    const void* __restrict__ x, const int* __restrict__ flag,
    float* __restrict__ invrms) {
  const int isf32 = *flag;
  const int t = blockIdx.x / NH;
  const int g = blockIdx.x % NH;
  const size_t base = ((size_t)(t * Cc + g * 64)) * Ss;
  float ss = 0.f;
  for (int v = threadIdx.x; v < 16384; v += 256) {
    const int ci = v >> 8;
    const int sj = (v & 255) << 3;
    float o[8];
    load8(x, base + (size_t)ci * Ss + sj, isf32, o);
#pragma unroll
    for (int e = 0; e < 8; e++) ss += o[e] * o[e];
  }
#pragma unroll
  for (int m = 1; m < 64; m <<= 1) ss += __shfl_xor(ss, m);
  __shared__ float red[4];
  if ((threadIdx.x & 63) == 0) red[threadIdx.x >> 6] = ss;
  __syncthreads();
  if (threadIdx.x == 0) {
    float tot = red[0] + red[1] + red[2] + red[3];
    invrms[blockIdx.x] = rsqrtf(tot * (1.f / 131072.f) + EPSV);
  }
}

// ---------------------------------------------------------------- kernel 2
__global__ __launch_bounds__(256) void norm_chunk_k(
    const void* __restrict__ x, const int* __restrict__ flag,
    const ushort_t* __restrict__ w1, const float* __restrict__ invrms,
    ushort_t* __restrict__ xnc, int s0c, int chl) {
  __shared__ __align__(16) ushort_t tile[64][64];
  const int isf32 = *flag;
  const int t = blockIdx.z;
  const int c0 = blockIdx.y * 64;
  const int sl0 = blockIdx.x * 64;
  const float ir = invrms[t * NH + (c0 >> 6)];
  const int tid = threadIdx.x;
  for (int v = tid; v < 512; v += 256) {
    const int ci = v >> 3;
    const int q = v & 7;
    float o[8];
    load8(x, ((size_t)(t * Cc + c0 + ci)) * Ss + s0c + sl0 + q * 8, isf32, o);
    const float sc = ir * b2f(w1[c0 + ci]);
    short8 w;
#pragma unroll
    for (int e = 0; e < 8; e++) w[e] = (short)f2b(o[e] * sc);
    *(short8*)&tile[ci][(q ^ (ci >> 3)) * 8] = w;
  }
  __syncthreads();
  for (int v = tid; v < 512; v += 256) {
    const int sj = v >> 3;
    const int cb = (v & 7) * 8;
    const int sw = (sj >> 3) ^ (v & 7);
    const int so = sj & 7;
    short8 o;
#pragma unroll
    for (int e = 0; e < 8; e++) o[e] = (short)tile[cb + e][sw * 8 + so];
    *(short8*)(xnc + ((size_t)(t * chl + sl0 + sj)) * Cc + c0 + cb) = o;
  }
}

// ---------------------------------------------------------------- kernel 3a
// (fallback for small-ws chunked path) 128x128 m97-pattern GEMM
__global__ __launch_bounds__(256, 2) void gemm_qkv_k(
    const ushort_t* __restrict__ A, const ushort_t* __restrict__ Bw,
    const ushort_t* __restrict__ bias, ushort_t* __restrict__ Cout) {
  __shared__ __align__(16) ushort_t As[128 * 32];
  __shared__ __align__(16) ushort_t Bs[128 * 32];
  const int tid = threadIdx.x;
  const int bm0 = blockIdx.x * 128;
  const int bn0 = blockIdx.y * 128;
  const int lane = tid & 63;
  const int wave = tid >> 6;
  const int wm = (wave >> 1) << 6;
  const int wn = (wave & 1) << 6;
  f32x4 acc[4][4];
#pragma unroll
  for (int i = 0; i < 4; i++)
#pragma unroll
    for (int j = 0; j < 4; j++) acc[i][j] = (f32x4){0.f, 0.f, 0.f, 0.f};
  const int srow = tid >> 2;
  const int scol = (tid & 3) << 3;
  const ushort_t* ag = A + (size_t)(bm0 + srow) * Cc + scol;
  const ushort_t* bg = Bw + (size_t)(bn0 + srow) * Cc + scol;
  ushort_t* la = As + tid * 8;
  ushort_t* lb = Bs + tid * 8;
  const int frow = lane & 15;
  const int koff = (lane >> 4) << 3;
  for (int kt = 0; kt < Cc; kt += 32) {
    __syncthreads();
    __builtin_amdgcn_global_load_lds(GLP(ag + kt), LDSP(la), 16, 0, 0);
    __builtin_amdgcn_global_load_lds(GLP(ag + kt + 64 * Cc), LDSP(la + 2048), 16, 0, 0);
    __builtin_amdgcn_global_load_lds(GLP(bg + kt), LDSP(lb), 16, 0, 0);
    __builtin_amdgcn_global_load_lds(GLP(bg + kt + 64 * Cc), LDSP(lb + 2048), 16, 0, 0);
    __syncthreads();
    short8 af[4], bf[4];
#pragma unroll
    for (int i = 0; i < 4; i++)
      af[i] = *(const short8*)(As + (wm + i * 16 + frow) * 32 + koff);
#pragma unroll
    for (int j = 0; j < 4; j++)
      bf[j] = *(const short8*)(Bs + (wn + j * 16 + frow) * 32 + koff);
#pragma unroll
    for (int i = 0; i < 4; i++)
#pragma unroll
      for (int j = 0; j < 4; j++)
        acc[i][j] = __builtin_amdgcn_mfma_f32_16x16x32_bf16(af[i], bf[j], acc[i][j], 0, 0, 0);
  }
  const int mq = (lane >> 4) << 2;
  const int nl = lane & 15;
#pragma unroll
  for (int j = 0; j < 4; j++) {
    const int col = bn0 + wn + j * 16 + nl;
    const float bc = b2f(bias[col]);
#pragma unroll
    for (int i = 0; i < 4; i++) {
#pragma unroll
      for (int r = 0; r < 4; r++) {
        const int row = bm0 + wm + i * 16 + mq + r;
        Cout[(size_t)row * N1 + col] = f2b(acc[i][j][r] + bc);
      }
    }
  }
}

// ---------------------------------------------------------------- kernel 3b
// 256x256 BK=64 8-wave GEMM, 8-phase counted-vmcnt pipeline (T1-T5), with
// full-line LDS-staged epilogue (R5: writes were 1.75x amplified by scalar
// 2B stores; dur tracked hbm_bytes/2.1TB/s across all schedules).
// K-loop LDS view: [buf][A|B][khalf][256x32] at pool offsets; epilogue view:
// per-wave 128x72-stride bf16 tile (72 keeps ds_read_b128 16B-aligned).
static __device__ __forceinline__ void rdA4(short8 af[4], const ushort_t* base,
                                            int ar, int mib, int ck) {
#pragma unroll
  for (int mi = 0; mi < 4; mi++)
    af[mi] = *(const short8*)&base[(ar + (mib + mi) * 16) * 32 + ck];
}
static __device__ __forceinline__ void rdB4(short8 bf[4], const ushort_t* base,
                                            int br, int ck) {
#pragma unroll
  for (int ni = 0; ni < 4; ni++)
    bf[ni] = *(const short8*)&base[(br + ni * 16) * 32 + ck];
}
template <int MIB>
static __device__ __forceinline__ void mmq(f32x4 (&acc)[8][4], const short8 af[4],
                                           const short8 bf[4]) {
#pragma unroll
  for (int mi = 0; mi < 4; mi++)
#pragma unroll
    for (int ni = 0; ni < 4; ni++)
      acc[MIB + mi][ni] = __builtin_amdgcn_mfma_f32_16x16x32_bf16(
          af[mi], bf[ni], acc[MIB + mi][ni], 0, 0, 0);
}
#define QPH_BAR { __builtin_amdgcn_sched_barrier(0); __builtin_amdgcn_s_barrier(); \
                  __builtin_amdgcn_sched_barrier(0); }
#define LDSOFF(p, ab, kh) ((((p) * 2 + (ab)) * 2 + (kh)) * 8192)

__global__ __launch_bounds__(512, 2) void gemm_qkv256_k(
    const ushort_t* __restrict__ A, const ushort_t* __restrict__ Bw,
    const ushort_t* __restrict__ bias, ushort_t* __restrict__ Cout) {
  __shared__ __align__(16) ushort_t pool[73728];  // 144 KiB: K-loop 128K / epi 8x(128x72)
  const int tid = threadIdx.x;
  const int lane = tid & 63;
  const int wave = tid >> 6;
  const int wr = wave >> 2;  // 0..1
  const int wc = wave & 3;   // 0..3
  // T1: XCD-bijective remap (1152 = 8*144), bn fast within chunk
  const int wg = ((int)blockIdx.x & 7) * 144 + ((int)blockIdx.x >> 3);
  const int bm0 = (wg / 9) * 256;
  const int bn0 = (wg % 9) * 256;
  // staging: thread t -> row = sub*128 + (t>>2), phys slot = t&3 (linear LDS),
  // logical slot = (t&3) ^ ((t>>3)&3) (inverse swizzle on global column)
  const int srow = tid >> 2;                              // 0..127
  const int scol = ((tid & 3) ^ ((tid >> 3) & 3)) << 3;   // elem 0..24
  const ushort_t* ag = A + (size_t)(bm0 + srow) * Cc + scol;
  const ushort_t* bg = Bw + (size_t)(bn0 + srow) * Cc + scol;
#define STGA(p, kh, kt) { \
    __builtin_amdgcn_global_load_lds(GLP(ag + (kt) + (kh) * 32), \
        LDSP(&pool[LDSOFF(p, 0, kh) + tid * 8]), 16, 0, 0); \
    __builtin_amdgcn_global_load_lds(GLP(ag + 128 * Cc + (kt) + (kh) * 32), \
        LDSP(&pool[LDSOFF(p, 0, kh) + 4096 + tid * 8]), 16, 0, 0); \
  }
#define STGB(p, kh, kt) { \
    __builtin_amdgcn_global_load_lds(GLP(bg + (kt) + (kh) * 32), \
        LDSP(&pool[LDSOFF(p, 1, kh) + tid * 8]), 16, 0, 0); \
    __builtin_amdgcn_global_load_lds(GLP(bg + 128 * Cc + (kt) + (kh) * 32), \
        LDSP(&pool[LDSOFF(p, 1, kh) + 4096 + tid * 8]), 16, 0, 0); \
  }
  // frag-read constants: row = base + (lane&15); phys slot = (lane>>4)^((lane>>1)&3)
  const int ck = (((lane >> 4) ^ ((lane >> 1) & 3)) << 3);
  const int ar = wr * 128 + (lane & 15);
  const int br = wc * 64 + (lane & 15);
  f32x4 acc[8][4];
#pragma unroll
  for (int i = 0; i < 8; i++)
#pragma unroll
    for (int j = 0; j < 4; j++) acc[i][j] = (f32x4){0.f, 0.f, 0.f, 0.f};
  short8 af[4], bf[4];
  // ---- prologue: stage tile 0 in stream order; kh0 landed, kh1 in flight
  STGA(0, 0, 0); STGB(0, 0, 0); STGA(0, 1, 0); STGB(0, 1, 0);
  asm volatile("s_waitcnt vmcnt(4)");
  QPH_BAR;
  // ---- main loop: tiles 0..10 (tile t+1 staged during tile t)
  for (int t = 0; t < 11; t++) {
    const int p = t & 1;
    const int q = p ^ 1;
    const int kt = (t + 1) * 64;
    // phase 0 (kh0): A mi0-3 + B ni0-3; stage A-kh0(t+1)
    rdA4(af, &pool[LDSOFF(p, 0, 0)], ar, 0, ck);
    rdB4(bf, &pool[LDSOFF(p, 1, 0)], br, ck);
    STGA(q, 0, kt);
    QPH_BAR;
    __builtin_amdgcn_s_setprio(1);
    mmq<0>(acc, af, bf);
    __builtin_amdgcn_s_setprio(0);
    QPH_BAR;
    // phase 1 (kh0): A mi4-7 (B reused); stage B-kh0(t+1); wait kh1(t)
    rdA4(af, &pool[LDSOFF(p, 0, 0)], ar, 4, ck);
    STGB(q, 0, kt);
    QPH_BAR;
    __builtin_amdgcn_s_setprio(1);
    mmq<4>(acc, af, bf);
    __builtin_amdgcn_s_setprio(0);
    __builtin_amdgcn_sched_barrier(0);
    asm volatile("s_waitcnt vmcnt(4)");   // tile t kh1 pair landed
    QPH_BAR;
    // phase 2 (kh1): A mi0-3 + B ni0-3; stage A-kh1(t+1)
    rdA4(af, &pool[LDSOFF(p, 0, 1)], ar, 0, ck);
    rdB4(bf, &pool[LDSOFF(p, 1, 1)], br, ck);
    STGA(q, 1, kt);
    QPH_BAR;
    __builtin_amdgcn_s_setprio(1);
    mmq<0>(acc, af, bf);
    __builtin_amdgcn_s_setprio(0);
    QPH_BAR;
    // phase 3 (kh1): A mi4-7; stage B-kh1(t+1); wait kh0(t+1)
    rdA4(af, &pool[LDSOFF(p, 0, 1)], ar, 4, ck);
    STGB(q, 1, kt);
    QPH_BAR;
    __builtin_amdgcn_s_setprio(1);
    mmq<4>(acc, af, bf);
    __builtin_amdgcn_s_setprio(0);
    __builtin_amdgcn_sched_barrier(0);
    asm volatile("s_waitcnt vmcnt(4)");   // tile t+1 kh0 pair landed
    QPH_BAR;
  }
  {  // ---- last tile t=11 (p=1): no staging; drain kh1 before phase 2
    rdA4(af, &pool[LDSOFF(1, 0, 0)], ar, 0, ck);
    rdB4(bf, &pool[LDSOFF(1, 1, 0)], br, ck);
    QPH_BAR;
    __builtin_amdgcn_s_setprio(1);
    mmq<0>(acc, af, bf);
    __builtin_amdgcn_s_setprio(0);
    QPH_BAR;
    rdA4(af, &pool[LDSOFF(1, 0, 0)], ar, 4, ck);
    QPH_BAR;
    __builtin_amdgcn_s_setprio(1);
    mmq<4>(acc, af, bf);
    __builtin_amdgcn_s_setprio(0);
    __builtin_amdgcn_sched_barrier(0);
    asm volatile("s_waitcnt vmcnt(0)");   // kh1 pair (last outstanding) landed
    QPH_BAR;
    rdA4(af, &pool[LDSOFF(1, 0, 1)], ar, 0, ck);
    rdB4(bf, &pool[LDSOFF(1, 1, 1)], br, ck);
    QPH_BAR;
    __builtin_amdgcn_s_setprio(1);
    mmq<0>(acc, af, bf);
    __builtin_amdgcn_s_setprio(0);
    QPH_BAR;
    rdA4(af, &pool[LDSOFF(1, 0, 1)], ar, 4, ck);
    __builtin_amdgcn_s_setprio(1);
    mmq<4>(acc, af, bf);
    __builtin_amdgcn_s_setprio(0);
  }
  // ---- epilogue via LDS: full-line 16B stores (R5 change)
  __builtin_amdgcn_sched_barrier(0);
  __syncthreads();   // waves 4-7's epi region overlaps buf1 read by others
  ushort_t* cw = pool + wave * 9216;   // 128 rows x 72 stride
  const int mq = (lane >> 4) << 2;
  const int nl = lane & 15;
#pragma unroll
  for (int ni = 0; ni < 4; ni++) {
    const float bc = b2f(bias[bn0 + wc * 64 + ni * 16 + nl]);
#pragma unroll
    for (int mi = 0; mi < 8; mi++) {
#pragma unroll
      for (int r = 0; r < 4; r++)
        cw[(mi * 16 + mq + r) * 72 + ni * 16 + nl] = f2b(acc[mi][ni][r] + bc);
    }
  }
  // per-wave region is private: compiler orders ds_write->ds_read via lgkmcnt
  const int rsub = lane >> 3;        // 0..7
  const int c8 = (lane & 7) * 8;     // 0,8,..,56
  ushort_t* outb = Cout + (size_t)(bm0 + wr * 128) * N1 + bn0 + wc * 64;
#pragma unroll
  for (int i = 0; i < 16; i++) {
    const int row = i * 8 + rsub;
    short8 v = *(const short8*)&cw[row * 72 + c8];
    *(short8*)(outb + (size_t)row * N1 + c8) = v;
  }
#undef STGA
#undef STGB
}

// ---------------------------------------------------------------- kernel 4
// wave-per-(sl,h): chl*12 independent 16x16x64 attention problems.
__global__ __launch_bounds__(256) void attention_k(
    const ushort_t* __restrict__ qkvc, const ushort_t* __restrict__ qs,
    const ushort_t* __restrict__ qb, const ushort_t* __restrict__ ks,
    const ushort_t* __restrict__ kb, const ushort_t* __restrict__ relb,
    ushort_t* __restrict__ aoc, int chl) {
  __shared__ __align__(16) float qf[4][16][68];
  __shared__ __align__(16) float kf[4][16][68];
  __shared__ __align__(16) float vf[4][16][68];
  __shared__ __align__(16) float attw[4][16][20];
  __shared__ __align__(16) float lnw[4][64];   // qs,qb,ks,kb fp32
  const int tid = threadIdx.x;
  const int wave = tid >> 6;
  const int lane = tid & 63;
  if (tid < 64) {
    lnw[0][tid] = b2f(qs[tid]);
    lnw[1][tid] = b2f(qb[tid]);
    lnw[2][tid] = b2f(ks[tid]);
    lnw[3][tid] = b2f(kb[tid]);
  }
  const int p = blockIdx.x * 4 + wave;
  const int sl = p / 12;
  const int h = p - sl * 12;
  const ushort_t* src = qkvc + (size_t)sl * N1 + h * 192;
  const size_t tstride = (size_t)chl * N1;
#pragma unroll
  for (int t = 0; t < 16; t++) {
    const ushort_t* r = src + (size_t)t * tstride;
    qf[wave][t][lane] = b2f(r[lane]);
    kf[wave][t][lane] = b2f(r[64 + lane]);
    vf[wave][t][lane] = b2f(r[128 + lane]);
  }
  __syncthreads();
  {
    const int row = lane >> 1;
    const int half = lane & 1;
    float* buf = (row < 16) ? &qf[wave][row][0] : &kf[wave][row - 16][0];
    const float* sc = (row < 16) ? lnw[0] : lnw[2];
    const float* bi = (row < 16) ? lnw[1] : lnw[3];
    f32x4* bp = (f32x4*)(buf + half * 32);
    f32x4 v4[8];
    float s = 0.f;
#pragma unroll
    for (int q4 = 0; q4 < 8; q4++) {
      v4[q4] = bp[q4];
      s += v4[q4][0] + v4[q4][1] + v4[q4][2] + v4[q4][3];
    }
    s += __shfl_xor(s, 1);
    const float mu = s * (1.f / 64.f);
    float va = 0.f;
#pragma unroll
    for (int q4 = 0; q4 < 8; q4++) {
#pragma unroll
      for (int e = 0; e < 4; e++) {
        const float d = v4[q4][e] - mu;
        va += d * d;
      }
    }
    va += __shfl_xor(va, 1);
    const float rs = rsqrtf(va * (1.f / 64.f) + EPSV);
    const f32x4* sc4 = (const f32x4*)(sc + half * 32);
    const f32x4* bi4 = (const f32x4*)(bi + half * 32);
#pragma unroll
    for (int q4 = 0; q4 < 8; q4++) {
      f32x4 scv = sc4[q4], biv = bi4[q4], o;
#pragma unroll
      for (int e = 0; e < 4; e++) o[e] = (v4[q4][e] - mu) * rs * scv[e] + biv[e];
      bp[q4] = o;
    }
  }
  __syncthreads();
  const int g = lane >> 4;
  const int t2 = lane & 15;
#pragma unroll
  for (int it = 0; it < 4; it++) {
    const int t1 = it * 4 + g;
    const f32x4* qrow = (const f32x4*)&qf[wave][t1][0];
    const f32x4* krow = (const f32x4*)&kf[wave][t2][0];
    float sco = 0.f;
#pragma unroll
    for (int q4 = 0; q4 < 16; q4++) {
      f32x4 a = qrow[q4], b = krow[q4];
      sco += a[0] * b[0] + a[1] * b[1] + a[2] * b[2] + a[3] * b[3];
    }
    const int rp = t2 - t1;
    int bkt = (rp > 0) ? 16 : 0;
    const int n = (rp < 0) ? -rp : rp;
    if (n < 8) {
      bkt += n;
    } else {
      int vl = 8 + (int)(__logf((float)n * 0.125f) * 2.8853900817779268f);
      bkt += (vl < 15) ? vl : 15;
    }
    sco = sco * 0.125f + b2f(relb[bkt * NH + h]);
    float mx = sco;
#pragma unroll
    for (int m = 8; m >= 1; m >>= 1) mx = fmaxf(mx, __shfl_xor(mx, m));
    const float ex = __expf(sco - mx);
    float sm = ex;
#pragma unroll
    for (int m = 8; m >= 1; m >>= 1) sm += __shfl_xor(sm, m);
    attw[wave][t1][t2] = ex / sm;
  }
  __syncthreads();
  const int jq = lane & 15;
#pragma unroll
  for (int it = 0; it < 4; it++) {
    const int t1 = it * 4 + g;
    const f32x4* arow2 = (const f32x4*)&attw[wave][t1][0];
    f32x4 o = (f32x4){0.f, 0.f, 0.f, 0.f};
#pragma unroll
    for (int tq = 0; tq < 4; tq++) {
      f32x4 aw = arow2[tq];
#pragma unroll
      for (int e = 0; e < 4; e++) {
        f32x4 vv = *(const f32x4*)&vf[wave][tq * 4 + e][jq * 4];
        o[0] += aw[e] * vv[0];
        o[1] += aw[e] * vv[1];
        o[2] += aw[e] * vv[2];
        o[3] += aw[e] * vv[3];
      }
    }
    short4v st;
#pragma unroll
    for (int e = 0; e < 4; e++) st[e] = (short)f2b(o[e]);
    *(short4v*)(aoc + ((size_t)(t1 * chl + sl)) * Cc + h * HD + jq * 4) = st;
  }
}

// ---------------------------------------------------------------- kernel 5
// D[c_out][r] = wo[c_out][:] . aoc[r][:]; fused +bias +residual -> y (f32)
__global__ __launch_bounds__(256, 2) void gemm_out_k(
    const ushort_t* __restrict__ A, const ushort_t* __restrict__ Bm,
    const ushort_t* __restrict__ bias, const void* __restrict__ xres,
    const int* __restrict__ flag, float* __restrict__ y, int s0c,
    int chl, int lgchl) {
  __shared__ __align__(16) ushort_t As[128 * 32];
  __shared__ __align__(16) ushort_t Bs[128 * 32];
  const int isf32 = *flag;
  const int tid = threadIdx.x;
  // XCD-bijective remap when grid divisible by 8; bm fast (shares aoc panel)
  int bmt = blockIdx.x, bnt = blockIdx.y;
  {
    const int nwg = gridDim.x * gridDim.y;
    if ((nwg & 7) == 0) {
      const int hw = (int)blockIdx.x + (int)blockIdx.y * gridDim.x;
      const int cpx = nwg >> 3;
      const int w = (hw & 7) * cpx + (hw >> 3);
      bmt = w % gridDim.x;
      bnt = w / gridDim.x;
    }
  }
  const int bm0 = bmt * 128;  // c_out
  const int bn0 = bnt * 128;  // r (chunk row)
  const int lane = tid & 63;
  const int wave = tid >> 6;
  const int wm = (wave >> 1) << 6;
  const int wn = (wave & 1) << 6;
  f32x4 acc[4][4];
#pragma unroll
  for (int i = 0; i < 4; i++)
#pragma unroll
    for (int j = 0; j < 4; j++) acc[i][j] = (f32x4){0.f, 0.f, 0.f, 0.f};
  const int srow = tid >> 2;
  const int scol = (tid & 3) << 3;
  const ushort_t* ag = A + (size_t)(bm0 + srow) * Cc + scol;
  const ushort_t* bg = Bm + (size_t)(bn0 + srow) * Cc + scol;
  ushort_t* la = As + tid * 8;
  ushort_t* lb = Bs + tid * 8;
  const int frow = lane & 15;
  const int koff = (lane >> 4) << 3;
  for (int kt = 0; kt < Cc; kt += 32) {
    __syncthreads();
    __builtin_amdgcn_global_load_lds(GLP(ag + kt), LDSP(la), 16, 0, 0);
    __builtin_amdgcn_global_load_lds(GLP(ag + kt + 64 * Cc), LDSP(la + 2048), 16, 0, 0);
    __builtin_amdgcn_global_load_lds(GLP(bg + kt), LDSP(lb), 16, 0, 0);
    __builtin_amdgcn_global_load_lds(GLP(bg + kt + 64 * Cc), LDSP(lb + 2048), 16, 0, 0);
    __syncthreads();
    short8 af[4], bf[4];
#pragma unroll
    for (int i = 0; i < 4; i++)
      af[i] = *(const short8*)(As + (wm + i * 16 + frow) * 32 + koff);
#pragma unroll
    for (int j = 0; j < 4; j++)
      bf[j] = *(const short8*)(Bs + (wn + j * 16 + frow) * 32 + koff);
#pragma unroll
    for (int i = 0; i < 4; i++)
#pragma unroll
      for (int j = 0; j < 4; j++)
        acc[i][j] = __builtin_amdgcn_mfma_f32_16x16x32_bf16(af[i], bf[j], acc[i][j], 0, 0, 0);
  }
  const int mq = (lane >> 4) << 2;
  const int nl = lane & 15;
#pragma unroll
  for (int j = 0; j < 4; j++) {
    const int col = bn0 + wn + j * 16 + nl;  // chunk row r
    const int t = col >> lgchl;              // r / chl
    const int sp = s0c + (col & (chl - 1));  // global spatial
#pragma unroll
    for (int i = 0; i < 4; i++) {
#pragma unroll
      for (int r = 0; r < 4; r++) {
        const int cch = bm0 + wm + i * 16 + mq + r;  // c_out
        const size_t off = ((size_t)(t * Cc + cch)) * Ss + sp;
        y[off] = acc[i][j][r] + b2f(bias[cch]) + load1(xres, off, isf32);
      }
    }
  }
}

// ----------------------------------------------------------------
extern "C" void kernel_launch(void* const* d_in, const int* in_sizes, int n_in,
                              void* d_out, int out_size, void* d_ws, size_t ws_size,
                              hipStream_t stream) {
  (void)in_sizes; (void)n_in; (void)out_size;
  const void* x   = d_in[0];
  const void* w1  = d_in[1];
  const void* win = d_in[2];
  const void* bin = d_in[3];
  const void* qsc = d_in[4];
  const void* qbi = d_in[5];
  const void* ksc = d_in[6];
  const void* kbi = d_in[7];
  const void* rbt = d_in[8];
  const void* wo  = d_in[9];
  const void* bo  = d_in[10];
  float* y = (float*)d_out;   // reference output dtype = float32

  char* ws = (char*)d_ws;
  int* flag      = (int*)ws;
  ushort_t* smallw = (ushort_t*)(ws + 4096);
  ushort_t* w1b  = smallw;
  ushort_t* binb = smallw + 768;
  ushort_t* bob  = smallw + 3072;
  ushort_t* qsb  = smallw + 3840;
  ushort_t* qbb  = smallw + 3904;
  ushort_t* ksb  = smallw + 3968;
  ushort_t* kbb  = smallw + 4032;
  ushort_t* relbb = smallw + 4096;
  float* invrms  = (float*)(ws + 1024);
  ushort_t* winb = (ushort_t*)(ws + 20480);
  ushort_t* wob  = (ushort_t*)(ws + 3559424);
  const size_t fixed = 4739072;  // end of wob

  // Adaptive chunk length (falls back to chunked schedule on small ws)
  const size_t per_row = (size_t)(Cc * 2 + N1 * 2 + Cc * 2);  // 7680 B
  int chl = Ss;
  while (chl > 64 && fixed + (size_t)Tt * chl * per_row > ws_size) chl >>= 1;
  int lgchl = 0;
  while ((1 << (lgchl + 1)) <= chl) lgchl++;

  ushort_t* xnc  = (ushort_t*)(ws + fixed);
  ushort_t* qkvc = xnc + (size_t)Tt * chl * Cc;
  ushort_t* aoc  = qkvc + (size_t)Tt * chl * N1;

  detect_k<<<1, 256, 0, stream>>>((const ushort_t*)x, flag);
  cvt_small_k<<<1, 256, 0, stream>>>(w1, bin, bo, qsc, qbi, ksc, kbi, rbt, smallw, flag);
  cvt_big_k<<<1769472 / 8 / 256, 256, 0, stream>>>(win, winb, 1769472 / 8, flag);
  cvt_big_k<<<589824 / 8 / 256, 256, 0, stream>>>(wo, wob, 589824 / 8, flag);
  rms_stats_k<<<dim3(Tt * NH), 256, 0, stream>>>(x, flag, invrms);
  for (int s0c = 0; s0c < Ss; s0c += chl) {
    norm_chunk_k<<<dim3(chl / 64, Cc / 64, Tt), 256, 0, stream>>>(x, flag, w1b, invrms, xnc, s0c, chl);
    if (chl == Ss) {
      // single-pass: M=32768 -> 128 x 9 = 1152 wgs (256^2 8-phase kernel)
      gemm_qkv256_k<<<dim3(1152), 512, 0, stream>>>(xnc, winb, binb, qkvc);
    } else {
      gemm_qkv_k<<<dim3(Tt * chl / 128, N1 / 128), 256, 0, stream>>>(xnc, winb, binb, qkvc);
    }
    attention_k<<<dim3(chl * NH / 4), 256, 0, stream>>>(qkvc, qsb, qbb, ksb, kbb, relbb, aoc, chl);
    gemm_out_k<<<dim3(Cc / 128, Tt * chl / 128), 256, 0, stream>>>(wob, aoc, bob, x, flag, y, s0c, chl, lgchl);
  }
}